// Round 7
// baseline (329.855 us; speedup 1.0000x reference)
//
#include <hip/hip_runtime.h>
#include <stdint.h>

using f32x4   = __attribute__((ext_vector_type(4))) float;
using short8  = __attribute__((ext_vector_type(8))) short;
using float4v = __attribute__((ext_vector_type(4))) float;
using float2v = __attribute__((ext_vector_type(2))) float;
using uint2v  = __attribute__((ext_vector_type(2))) unsigned int;
using uint4v  = __attribute__((ext_vector_type(4))) unsigned int;

#define NCOL 11008
#define KDIM 4096
#define LSTRIDE 264   // LDS bytes per k-row: 128 cols * 2B + 8B pad (2-way reads)

__device__ __forceinline__ unsigned pk_bf16(float a, float b) {
  unsigned ua = __float_as_uint(a); ua += 0x7fffu + ((ua >> 16) & 1u);  // RNE
  unsigned ub = __float_as_uint(b); ub += 0x7fffu + ((ub >> 16) & 1u);
  return (ua >> 16) | (ub & 0xffff0000u);
}

// ---- kernel 1: mask (fp64-exact, same decisions as R5-green) + write
//      mask-zeroed bf16 copy of x into ws.  grid (8 rb, 8 kgrp), 256 thr.
//      Thread t covers cols g*512 + 2t (+1); kb-local = t>>5.
__global__ __launch_bounds__(256) void mask_convert_kernel(
    const float* __restrict__ x, unsigned* __restrict__ xbf) {
  const int rb = blockIdx.x;
  const int g  = blockIdx.y;
  const int t  = threadIdx.x;
  __shared__ double part[256];
  __shared__ unsigned sh_bits;

  const float* base = x + (size_t)rb * 16 * KDIM + g * 512 + t * 2;
  double s = 0.0;
#pragma unroll
  for (int r = 0; r < 16; ++r) {
    float2v a = *(const float2v*)(base + (size_t)r * KDIM);
    s += (double)fabsf(a[0]) + (double)fabsf(a[1]);
  }
  part[t] = s;
  __syncthreads();
  if (t < 8) {                        // t = kb-local (8 kbs per 512-col group)
    double acc = 0.0;
#pragma unroll
    for (int u = 0; u < 32; ++u) acc += part[t * 32 + u];
    bool on = (acc * (1.0 / 1024.0)) > (double)0.8f;
    unsigned long long bal = __ballot(on);
    if (t == 0) sh_bits = (unsigned)(bal & 0xffu);
  }
  __syncthreads();
  const unsigned keep = (sh_bits >> (t >> 5)) & 1u;

  unsigned* dst = xbf + (size_t)rb * 16 * (KDIM / 2) + g * 256 + t;
#pragma unroll
  for (int r = 0; r < 16; ++r) {      // reload (L1-hot) + pack/zero + store
    float2v a = *(const float2v*)(base + (size_t)r * KDIM);
    dst[(size_t)r * (KDIM / 2)] = keep ? pk_bf16(a[0], a[1]) : 0u;
  }
}

// ---- kernel 2: dense GEMM, M=128 x N=128 per block, K split 8 ways.
// grid (86 n-tiles, 8 kz), 256 thr (4 waves). W fetched exactly once chip-wide.
// Wave wv owns cols [wv*32,+32) as even/odd frags; 8 m-tiles (all 128 rows).
// Epilogue: global_atomic_add_f32 onto memset-0 out; kz==0 adds bias.
__global__ __launch_bounds__(256) void gemm_kernel(
    const unsigned* __restrict__ xbf, const float* __restrict__ w,
    const float* __restrict__ bias, float* __restrict__ out) {

  __shared__ __align__(16) uint8_t lds[64 * LSTRIDE];

  const int tid  = threadIdx.x;
  const int lane = tid & 63;
  const int wv   = tid >> 6;
  const int c    = lane & 15;
  const int q    = lane >> 4;
  const int n0   = blockIdx.x * 128;
  const int kz   = blockIdx.y;        // k-range [kz*512, kz*512+512)

  f32x4 acc[8][2] = {};               // [m-tile][even/odd]

  // W staging: thread t -> k = r*8 + (t>>5), n = (t&31)*4
  const int sk = tid >> 5;
  const int sn = (tid & 31) * 4;
  uint8_t* wS = lds + (size_t)sk * LSTRIDE + sn * 2;

  float4v wr[8];
#define ISSUE_W(KB)                                                      \
  {                                                                      \
    const float* wp = w + (size_t)(kz * 512 + (KB)*64 + sk) * NCOL + n0 + sn; \
    _Pragma("unroll")                                                    \
    for (int r = 0; r < 8; ++r)                                          \
      wr[r] = *(const float4v*)(wp + (size_t)r * 8 * NCOL);              \
  }

  // A source: uint4 index = row*512 + kz*64 + kb*8 + ks*4 + q, row = mt*16+c
  const uint4v* aBase = (const uint4v*)xbf + (size_t)c * 512 + kz * 64 + q;

  ISSUE_W(0);
  for (int kb = 0; kb < 8; ++kb) {
    __syncthreads();                  // prior compute done with LDS
#pragma unroll
    for (int r = 0; r < 8; ++r) {     // vmcnt wait on wr lands here
      uint2v v;
      v[0] = pk_bf16(wr[r][0], wr[r][1]);
      v[1] = pk_bf16(wr[r][2], wr[r][3]);
      *(uint2v*)(wS + (size_t)r * 8 * LSTRIDE) = v;
    }
    __syncthreads();
    if (kb < 7) ISSUE_W(kb + 1);      // prefetch overlaps compute

#pragma unroll
    for (int ks = 0; ks < 2; ++ks) {
      // A fragments first (L2-hot ws reads get latency overlap with repack)
      union { uint4v u; short8 v; } am[8];
#pragma unroll
      for (int mt = 0; mt < 8; ++mt)
        am[mt].u = aBase[(size_t)mt * 16 * 512 + kb * 8 + ks * 4];

      // B fragments: dword j = cols (2c,2c+1) at k = ks*32 + q*8 + j
      const uint8_t* wb = lds + (size_t)(ks * 32 + q * 8) * LSTRIDE + (wv * 32 + 2 * c) * 2;
      unsigned wj[8];
#pragma unroll
      for (int j = 0; j < 8; ++j)
        wj[j] = *(const unsigned*)(wb + (size_t)j * LSTRIDE);
      union { short8 v; unsigned u[4]; } be, bo;
#pragma unroll
      for (int p = 0; p < 4; ++p) {
        be.u[p] = (wj[2 * p] & 0x0000ffffu) | (wj[2 * p + 1] << 16);   // even col
        bo.u[p] = (wj[2 * p] >> 16) | (wj[2 * p + 1] & 0xffff0000u);   // odd col
      }
#pragma unroll
      for (int mt = 0; mt < 8; ++mt) {
        acc[mt][0] = __builtin_amdgcn_mfma_f32_16x16x32_bf16(am[mt].v, be.v, acc[mt][0], 0, 0, 0);
        acc[mt][1] = __builtin_amdgcn_mfma_f32_16x16x32_bf16(am[mt].v, bo.v, acc[mt][1], 0, 0, 0);
      }
    }
  }
#undef ISSUE_W

  // epilogue: D row = mt*16 + q*4 + p, cols (2c,2c+1); atomic accumulate
  const int colE = n0 + wv * 32 + 2 * c;
  const float bE = (kz == 0) ? bias[colE] : 0.f;
  const float bO = (kz == 0) ? bias[colE + 1] : 0.f;
#pragma unroll
  for (int mt = 0; mt < 8; ++mt) {
#pragma unroll
    for (int p = 0; p < 4; ++p) {
      const int row = mt * 16 + q * 4 + p;
      float* o = out + (size_t)row * NCOL + colE;
      unsafeAtomicAdd(o,     acc[mt][0][p] + bE);
      unsafeAtomicAdd(o + 1, acc[mt][1][p] + bO);
    }
  }
}

extern "C" void kernel_launch(void* const* d_in, const int* in_sizes, int n_in,
                              void* d_out, int out_size, void* d_ws, size_t ws_size,
                              hipStream_t stream) {
  const float* x    = (const float*)d_in[0];
  const float* w    = (const float*)d_in[1];
  const float* bias = (const float*)d_in[2];
  float* out        = (float*)d_out;
  unsigned* xbf     = (unsigned*)d_ws;    // 128 x 4096 bf16 (1 MiB)

  hipLaunchKernelGGL(mask_convert_kernel, dim3(8, 8), dim3(256), 0, stream, x, xbf);
  hipMemsetAsync(out, 0, (size_t)out_size * sizeof(float), stream);
  hipLaunchKernelGGL(gemm_kernel, dim3(86, 8), dim3(256), 0, stream,
                     xbf, w, bias, out);
}